// Round 3
// baseline (537.106 us; speedup 1.0000x reference)
//
#include <hip/hip_runtime.h>

// ---------------------------------------------------------------------------
// ResidualAttentionBlock: LN1 -> QKV -> MHA(12 heads, Dh=64) -> out+res ->
//                         LN2 -> FC(4E)+QuickGELU -> proj+res
// R3: flash — register-prefetched K/V staging (global latency hidden behind
//     compute), swizzled conflict-free P layout (PSTR=128, chunk^=(row>>1)&7),
//     P aliased over K (50.2KB LDS, 3 blocks/CU). GEMM: TN=64 variant for
//     N=768 outputs (grid 768 = 3 blocks/CU exactly).
// ---------------------------------------------------------------------------

#define E 768
#define LSEQ 2048

typedef short bfrag __attribute__((ext_vector_type(8)));   // 8 bf16 = 4 VGPRs
typedef float facc  __attribute__((ext_vector_type(4)));   // 4 fp32 acc

__device__ __forceinline__ unsigned short f2bf(float f) {
  unsigned int u = __float_as_uint(f);
  u = (u + 0x7fffu + ((u >> 16) & 1u)) >> 16;   // RNE
  return (unsigned short)u;
}

__device__ __forceinline__ facc mfma16(bfrag a, bfrag b, facc c) {
  return __builtin_amdgcn_mfma_f32_16x16x32_bf16(a, b, c, 0, 0, 0);
}

__device__ __forceinline__ void gl2lds16(const void* g, void* l) {
  __builtin_amdgcn_global_load_lds((__attribute__((address_space(1))) void*)g,
                                   (__attribute__((address_space(3))) void*)l,
                                   16, 0, 0);
}

// --------------------------- fp32 -> bf16 cast ------------------------------
__global__ __launch_bounds__(256) void cvt_bf16_k(const float* __restrict__ s,
                                                  unsigned short* __restrict__ d) {
  int i = (blockIdx.x * 256 + threadIdx.x) * 4;
  float4 v = *(const float4*)(s + i);
  uint2 o;
  o.x = (unsigned)f2bf(v.x) | ((unsigned)f2bf(v.y) << 16);
  o.y = (unsigned)f2bf(v.z) | ((unsigned)f2bf(v.w) << 16);
  *(uint2*)(d + i) = o;
}

// --------------------------- LayerNorm (fp32 in, bf16 out) ------------------
__global__ __launch_bounds__(256) void ln_bf16_k(const float* __restrict__ x,
                                                 const float* __restrict__ w,
                                                 const float* __restrict__ b,
                                                 unsigned short* __restrict__ out) {
  int row = blockIdx.x * 4 + (threadIdx.x >> 6);
  int lane = threadIdx.x & 63;
  const float* xr = x + row * E;
  float4 v[3];
  float s = 0.f, ss = 0.f;
#pragma unroll
  for (int i = 0; i < 3; ++i) {
    v[i] = *(const float4*)(xr + i * 256 + lane * 4);
    s += v[i].x + v[i].y + v[i].z + v[i].w;
    ss += v[i].x * v[i].x + v[i].y * v[i].y + v[i].z * v[i].z + v[i].w * v[i].w;
  }
#pragma unroll
  for (int m = 32; m; m >>= 1) { s += __shfl_xor(s, m); ss += __shfl_xor(ss, m); }
  float mu = s * (1.f / E);
  float rstd = rsqrtf(ss * (1.f / E) - mu * mu + 1e-5f);
#pragma unroll
  for (int i = 0; i < 3; ++i) {
    int c = i * 256 + lane * 4;
    float4 wv = *(const float4*)(w + c);
    float4 bv = *(const float4*)(b + c);
    float y0 = (v[i].x - mu) * rstd * wv.x + bv.x;
    float y1 = (v[i].y - mu) * rstd * wv.y + bv.y;
    float y2 = (v[i].z - mu) * rstd * wv.z + bv.z;
    float y3 = (v[i].w - mu) * rstd * wv.w + bv.w;
    uint2 o;
    o.x = (unsigned)f2bf(y0) | ((unsigned)f2bf(y1) << 16);
    o.y = (unsigned)f2bf(y2) | ((unsigned)f2bf(y3) << 16);
    *(uint2*)(out + row * E + c) = o;
  }
}

// --------------------------- GEMM: C[M,N] = A[M,K] * W[N,K]^T + epilogue ----
// TN=128: 128x128 tile. TN=64: 128x64 tile (for N=768: grid 64x12=768 blocks
// = 3 blocks/CU exactly; 128x128 gave 384 blocks = half-empty CUs).
template <int MODE, int TN>
__global__ __launch_bounds__(256) void gemm_bt(const unsigned short* __restrict__ A,
                                               const unsigned short* __restrict__ Bw,
                                               const float* __restrict__ bias,
                                               const float* __restrict__ resid,
                                               void* __restrict__ Cout, int K, int N) {
  __shared__ unsigned short Al[128 * 32];
  __shared__ unsigned short Bl[TN * 32];
  constexpr int NI = TN / 32;
  int tid = threadIdx.x;
  int lane = tid & 63, w = tid >> 6;
  int q4 = lane >> 4, m16 = lane & 15;
  int m0 = blockIdx.x * 128, n0 = blockIdx.y * TN;
  int wm = (w >> 1) * 64, wn = (w & 1) * (TN / 2);
  facc zf = {0.f, 0.f, 0.f, 0.f};
  facc acc[4][NI];
#pragma unroll
  for (int mi = 0; mi < 4; ++mi)
#pragma unroll
    for (int ni = 0; ni < NI; ++ni) acc[mi][ni] = zf;

  for (int k0 = 0; k0 < K; k0 += 32) {
    int c0 = tid, c1 = tid + 256;
    gl2lds16(A + (m0 + (c0 >> 2)) * K + k0 + (c0 & 3) * 8, &Al[c0 * 8]);
    gl2lds16(A + (m0 + (c1 >> 2)) * K + k0 + (c1 & 3) * 8, &Al[c1 * 8]);
    gl2lds16(Bw + (n0 + (c0 >> 2)) * K + k0 + (c0 & 3) * 8, &Bl[c0 * 8]);
    if constexpr (TN == 128)
      gl2lds16(Bw + (n0 + (c1 >> 2)) * K + k0 + (c1 & 3) * 8, &Bl[c1 * 8]);
    __syncthreads();
    bfrag a[4], bb[NI];
#pragma unroll
    for (int mi = 0; mi < 4; ++mi)
      a[mi] = *(const bfrag*)&Al[(wm + mi * 16 + m16) * 32 + q4 * 8];
#pragma unroll
    for (int ni = 0; ni < NI; ++ni)
      bb[ni] = *(const bfrag*)&Bl[(wn + ni * 16 + m16) * 32 + q4 * 8];
#pragma unroll
    for (int mi = 0; mi < 4; ++mi)
#pragma unroll
      for (int ni = 0; ni < NI; ++ni)
        acc[mi][ni] = mfma16(a[mi], bb[ni], acc[mi][ni]);
    __syncthreads();
  }

#pragma unroll
  for (int mi = 0; mi < 4; ++mi)
#pragma unroll
    for (int ni = 0; ni < NI; ++ni)
#pragma unroll
      for (int r = 0; r < 4; ++r) {
        int row = m0 + wm + mi * 16 + q4 * 4 + r;
        int col = n0 + wn + ni * 16 + m16;
        float vv = acc[mi][ni][r] + bias[col];
        if constexpr (MODE == 1) {
          ((float*)Cout)[row * N + col] = vv + resid[row * N + col];
        } else if constexpr (MODE == 2) {
          float g = vv / (1.f + __expf(-1.702f * vv));
          ((unsigned short*)Cout)[row * N + col] = f2bf(g);
        } else {
          ((unsigned short*)Cout)[row * N + col] = f2bf(vv);
        }
      }
}

// --------------------------- V transpose ------------------------------------
__global__ __launch_bounds__(256) void vtrans_k(const unsigned short* __restrict__ qkv,
                                                unsigned short* __restrict__ vt) {
  __shared__ unsigned short T[64 * 72];
  int tid = threadIdx.x;
  int l0 = blockIdx.x * 64;
  int by = blockIdx.y;
  int n = by & 3, h = by >> 2;
#pragma unroll
  for (int i = 0; i < 2; ++i) {
    int u = i * 256 + tid;
    int r = u >> 3, c8 = u & 7;
    uint4 v4 = *(const uint4*)(qkv + ((l0 + r) * 4 + n) * 2304 + 1536 + h * 64 + c8 * 8);
    *(uint4*)&T[r * 72 + c8 * 8] = v4;
  }
  __syncthreads();
#pragma unroll
  for (int i = 0; i < 2; ++i) {
    int u = i * 256 + tid;
    int d = u >> 3, c8 = u & 7;
    unsigned short e[8];
#pragma unroll
    for (int jj = 0; jj < 8; ++jj) {
      int j = jj ^ (c8 & 7);
      e[j] = T[(c8 * 8 + j) * 72 + d];
    }
    uint4 o4;
    o4.x = (unsigned)e[0] | ((unsigned)e[1] << 16);
    o4.y = (unsigned)e[2] | ((unsigned)e[3] << 16);
    o4.z = (unsigned)e[4] | ((unsigned)e[5] << 16);
    o4.w = (unsigned)e[6] | ((unsigned)e[7] << 16);
    *(uint4*)(vt + ((size_t)by * 64 + d) * 2048 + l0 + c8 * 8) = o4;
  }
}

// --------------------------- Flash attention --------------------------------
// grid (16 q-tiles of 128, 48 by=(h*4+n)); 4 waves, 32 q-rows each.
// K tile in KP (stride 88); P overlays KP with swizzled stride-128 layout:
//   elem(row,col) at row*128 + ((col>>3 ^ (row>>1)&7)<<3) + (col&7)
//   -> q4 lane-groups hit disjoint 8-bank windows: conflict-free b16 writes.
// K/V of tile t+1 prefetched into VGPRs during compute of tile t.
#define KSTR 88
#define VSTR 136
__global__ __launch_bounds__(256) void flash_k(const unsigned short* __restrict__ qkv,
                                               const unsigned short* __restrict__ vt,
                                               unsigned short* __restrict__ o) {
  __shared__ unsigned short KP[16384];        // 32KB: K (stride 88) / P (stride 128)
  __shared__ unsigned short Vt[64 * VSTR];    // 17.4KB: V^T [d][kv]
  int tid = threadIdx.x;
  int lane = tid & 63, w = tid >> 6;
  int q4 = lane >> 4, m16 = lane & 15;
  int qt = blockIdx.x;
  int by = blockIdx.y;
  int n = by & 3, h = by >> 2;
  const unsigned short* vtb = vt + (size_t)by * 64 * 2048;

  // Q fragments (A-layout), registers across the kv loop
  bfrag qf[2][2];
#pragma unroll
  for (int mi = 0; mi < 2; ++mi) {
    int l = qt * 128 + w * 32 + mi * 16 + m16;
#pragma unroll
    for (int ki = 0; ki < 2; ++ki)
      qf[mi][ki] = *(const bfrag*)(qkv + ((size_t)(l * 4 + n)) * 2304 + h * 64 + ki * 32 + q4 * 8);
  }

  // precomputed swizzled P read offsets (elements), constant across tiles
  int paOff[2][4];
#pragma unroll
  for (int mi = 0; mi < 2; ++mi) {
    int row = w * 32 + mi * 16 + m16;
    int fr = (row >> 1) & 7;
#pragma unroll
    for (int ki = 0; ki < 4; ++ki)
      paOff[mi][ki] = row * 128 + (((ki * 4 + q4) ^ fr) << 3);
  }

  facc zf = {0.f, 0.f, 0.f, 0.f};
  facc accO[2][4];
#pragma unroll
  for (int mi = 0; mi < 2; ++mi)
#pragma unroll
    for (int di = 0; di < 4; ++di) accO[mi][di] = zf;
  float lrow[2][4];
#pragma unroll
  for (int mi = 0; mi < 2; ++mi)
#pragma unroll
    for (int r = 0; r < 4; ++r) lrow[mi][r] = 0.f;

  const float cs = 0.125f * 1.44269504088896f;  // scale * log2(e)

  // staging address components (per thread)
  int ur[4], uc[4], vd[4], vu[4];
#pragma unroll
  for (int i = 0; i < 4; ++i) {
    int u = i * 256 + tid;
    ur[i] = u >> 3;  uc[i] = u & 7;    // K: row, 16B-chunk
    vd[i] = u >> 4;  vu[i] = u & 15;   // Vt: d-row, 16B-chunk
  }

  uint4 kreg[4], vreg[4];
  // prologue: load + stage tile 0
#pragma unroll
  for (int i = 0; i < 4; ++i) {
    kreg[i] = *(const uint4*)(qkv + ((size_t)(ur[i] * 4 + n)) * 2304 + 768 + h * 64 + uc[i] * 8);
    vreg[i] = *(const uint4*)(vtb + vd[i] * 2048 + vu[i] * 8);
  }
#pragma unroll
  for (int i = 0; i < 4; ++i) {
    *(uint4*)&KP[ur[i] * KSTR + uc[i] * 8] = kreg[i];
    *(uint4*)&Vt[vd[i] * VSTR + vu[i] * 8] = vreg[i];
  }
  __syncthreads();

  for (int kt = 0; kt < 16; ++kt) {
    // prefetch tile kt+1 into registers (consumed after PV)
    if (kt < 15) {
      int kvn = (kt + 1) * 128;
#pragma unroll
      for (int i = 0; i < 4; ++i) {
        kreg[i] = *(const uint4*)(qkv + ((size_t)((kvn + ur[i]) * 4 + n)) * 2304 + 768 + h * 64 + uc[i] * 8);
        vreg[i] = *(const uint4*)(vtb + vd[i] * 2048 + kvn + vu[i] * 8);
      }
    }

    // S = Q K^T : per wave 32x128 = 2(mi) x 8(ni), K=64 (2 steps)
    facc S[2][8];
#pragma unroll
    for (int mi = 0; mi < 2; ++mi)
#pragma unroll
      for (int ni = 0; ni < 8; ++ni) S[mi][ni] = zf;
#pragma unroll
    for (int ni = 0; ni < 8; ++ni)
#pragma unroll
      for (int ki = 0; ki < 2; ++ki) {
        bfrag bk = *(const bfrag*)&KP[(ni * 16 + m16) * KSTR + ki * 32 + q4 * 8];
#pragma unroll
        for (int mi = 0; mi < 2; ++mi)
          S[mi][ni] = mfma16(qf[mi][ki], bk, S[mi][ni]);
      }
    __syncthreads();   // all K reads done before P overwrites

    // softmax (no max subtraction) + swizzled P writes (conflict-free)
#pragma unroll
    for (int mi = 0; mi < 2; ++mi)
#pragma unroll
      for (int r = 0; r < 4; ++r) {
        int prow = w * 32 + mi * 16 + q4 * 4 + r;
        int fw = (prow >> 1) & 7;
        int base = prow * 128 + (m16 & 7);
        int chi = m16 >> 3;
        float ls = 0.f;
#pragma unroll
        for (int ni = 0; ni < 8; ++ni) {
          float p = __builtin_amdgcn_exp2f(S[mi][ni][r] * cs);
          ls += p;
          KP[base + ((((ni * 2 + chi) ^ fw)) << 3)] = (unsigned short)(__float_as_uint(p) >> 16);
        }
        lrow[mi][r] += ls;
      }

    // O += P @ V : per wave 32x64, K=128 (4 steps); own-wave P rows only
#pragma unroll
    for (int ki = 0; ki < 4; ++ki) {
      bfrag pa[2];
#pragma unroll
      for (int mi = 0; mi < 2; ++mi)
        pa[mi] = *(const bfrag*)&KP[paOff[mi][ki]];
#pragma unroll
      for (int di = 0; di < 4; ++di) {
        bfrag bv = *(const bfrag*)&Vt[(di * 16 + m16) * VSTR + ki * 32 + q4 * 8];
#pragma unroll
        for (int mi = 0; mi < 2; ++mi)
          accO[mi][di] = mfma16(pa[mi], bv, accO[mi][di]);
      }
    }
    __syncthreads();   // P/Vt reads done before restage

    if (kt < 15) {
#pragma unroll
      for (int i = 0; i < 4; ++i) {
        *(uint4*)&KP[ur[i] * KSTR + uc[i] * 8] = kreg[i];
        *(uint4*)&Vt[vd[i] * VSTR + vu[i] * 8] = vreg[i];
      }
      __syncthreads();
    }
  }

  // epilogue: reduce l across the 16 lanes sharing each row, write O
#pragma unroll
  for (int mi = 0; mi < 2; ++mi)
#pragma unroll
    for (int r = 0; r < 4; ++r) {
      float ls = lrow[mi][r];
      ls += __shfl_xor(ls, 1);
      ls += __shfl_xor(ls, 2);
      ls += __shfl_xor(ls, 4);
      ls += __shfl_xor(ls, 8);
      float inv = 1.f / ls;
      int l = qt * 128 + w * 32 + mi * 16 + q4 * 4 + r;
#pragma unroll
      for (int di = 0; di < 4; ++di) {
        int col = h * 64 + di * 16 + m16;
        o[(size_t)(l * 4 + n) * 768 + col] = f2bf(accO[mi][di][r] * inv);
      }
    }
}

// --------------------------- launcher ---------------------------------------
extern "C" void kernel_launch(void* const* d_in, const int* in_sizes, int n_in,
                              void* d_out, int out_size, void* d_ws, size_t ws_size,
                              hipStream_t stream) {
  (void)in_sizes; (void)n_in; (void)out_size; (void)ws_size;
  const float* x      = (const float*)d_in[0];
  const float* ln1_w  = (const float*)d_in[1];
  const float* ln1_b  = (const float*)d_in[2];
  const float* w_qkv  = (const float*)d_in[3];
  const float* b_qkv  = (const float*)d_in[4];
  const float* w_out  = (const float*)d_in[5];
  const float* b_out  = (const float*)d_in[6];
  const float* ln2_w  = (const float*)d_in[7];
  const float* ln2_b  = (const float*)d_in[8];
  const float* w_fc   = (const float*)d_in[9];
  const float* b_fc   = (const float*)d_in[10];
  const float* w_proj = (const float*)d_in[11];
  const float* b_proj = (const float*)d_in[12];

  char* ws = (char*)d_ws;
  unsigned short* qkv_bf  = (unsigned short*)(ws);
  unsigned short* o_bf    = (unsigned short*)(ws + 37748736);
  unsigned short* f_bf    = (unsigned short*)(ws);
  unsigned short* h_bf    = (unsigned short*)(ws + 50331648);
  float*          x1      = (float*)        (ws + 62914560);
  unsigned short* vt      = (unsigned short*)(ws + 62914560);  // dead before x1 written
  unsigned short* wqkv_bf = (unsigned short*)(ws + 88080384);
  unsigned short* wout_bf = (unsigned short*)(ws + 91619328);
  unsigned short* wfc_bf  = (unsigned short*)(ws + 92798976);
  unsigned short* wproj_bf= (unsigned short*)(ws + 97517568);

  cvt_bf16_k<<<1728, 256, 0, stream>>>(w_qkv,  wqkv_bf);
  cvt_bf16_k<<<576,  256, 0, stream>>>(w_out,  wout_bf);
  cvt_bf16_k<<<2304, 256, 0, stream>>>(w_fc,   wfc_bf);
  cvt_bf16_k<<<2304, 256, 0, stream>>>(w_proj, wproj_bf);

  ln_bf16_k<<<2048, 256, 0, stream>>>(x, ln1_w, ln1_b, h_bf);
  gemm_bt<0, 128><<<dim3(64, 18), 256, 0, stream>>>(h_bf, wqkv_bf, b_qkv, nullptr, qkv_bf, 768, 2304);
  vtrans_k<<<dim3(32, 48), 256, 0, stream>>>(qkv_bf, vt);
  flash_k<<<dim3(16, 48), 256, 0, stream>>>(qkv_bf, vt, o_bf);
  gemm_bt<1, 64><<<dim3(64, 12), 256, 0, stream>>>(o_bf, wout_bf, b_out, x, x1, 768, 768);
  ln_bf16_k<<<2048, 256, 0, stream>>>(x1, ln2_w, ln2_b, h_bf);
  gemm_bt<2, 128><<<dim3(64, 24), 256, 0, stream>>>(h_bf, wfc_bf, b_fc, nullptr, f_bf, 768, 3072);
  gemm_bt<1, 64><<<dim3(64, 12), 256, 0, stream>>>(f_bf, wproj_bf, b_proj, x1, (float*)d_out, 3072, 768);
}

// Round 4
// 455.674 us; speedup vs baseline: 1.1787x; 1.1787x over previous
//
#include <hip/hip_runtime.h>

// ---------------------------------------------------------------------------
// ResidualAttentionBlock: LN1 -> QKV -> MHA(12 heads, Dh=64) -> out+res ->
//                         LN2 -> FC(4E)+QuickGELU -> proj+res
// R4: flash v3 — async gl2lds staging (no VGPR prefetch: R3's spill regression),
//     K restaged mid-tile / V at tile top (latency hidden, single-buffered),
//     sliced softmax+PV with per-wave private P (no barrier), XOR-swizzled
//     source addressing so unpadded stride-64/128 reads are conflict-free.
//     LDS 43KB -> 3 blocks/CU. GEMMs unchanged from R3 (TN=64 kept: helped).
// ---------------------------------------------------------------------------

#define E 768
#define LSEQ 2048

typedef short bfrag __attribute__((ext_vector_type(8)));   // 8 bf16 = 4 VGPRs
typedef float facc  __attribute__((ext_vector_type(4)));   // 4 fp32 acc

__device__ __forceinline__ unsigned short f2bf(float f) {
  unsigned int u = __float_as_uint(f);
  u = (u + 0x7fffu + ((u >> 16) & 1u)) >> 16;   // RNE
  return (unsigned short)u;
}

__device__ __forceinline__ facc mfma16(bfrag a, bfrag b, facc c) {
  return __builtin_amdgcn_mfma_f32_16x16x32_bf16(a, b, c, 0, 0, 0);
}

__device__ __forceinline__ void gl2lds16(const void* g, void* l) {
  __builtin_amdgcn_global_load_lds((__attribute__((address_space(1))) void*)g,
                                   (__attribute__((address_space(3))) void*)l,
                                   16, 0, 0);
}

// --------------------------- fp32 -> bf16 cast ------------------------------
__global__ __launch_bounds__(256) void cvt_bf16_k(const float* __restrict__ s,
                                                  unsigned short* __restrict__ d) {
  int i = (blockIdx.x * 256 + threadIdx.x) * 4;
  float4 v = *(const float4*)(s + i);
  uint2 o;
  o.x = (unsigned)f2bf(v.x) | ((unsigned)f2bf(v.y) << 16);
  o.y = (unsigned)f2bf(v.z) | ((unsigned)f2bf(v.w) << 16);
  *(uint2*)(d + i) = o;
}

// --------------------------- LayerNorm (fp32 in, bf16 out) ------------------
__global__ __launch_bounds__(256) void ln_bf16_k(const float* __restrict__ x,
                                                 const float* __restrict__ w,
                                                 const float* __restrict__ b,
                                                 unsigned short* __restrict__ out) {
  int row = blockIdx.x * 4 + (threadIdx.x >> 6);
  int lane = threadIdx.x & 63;
  const float* xr = x + row * E;
  float4 v[3];
  float s = 0.f, ss = 0.f;
#pragma unroll
  for (int i = 0; i < 3; ++i) {
    v[i] = *(const float4*)(xr + i * 256 + lane * 4);
    s += v[i].x + v[i].y + v[i].z + v[i].w;
    ss += v[i].x * v[i].x + v[i].y * v[i].y + v[i].z * v[i].z + v[i].w * v[i].w;
  }
#pragma unroll
  for (int m = 32; m; m >>= 1) { s += __shfl_xor(s, m); ss += __shfl_xor(ss, m); }
  float mu = s * (1.f / E);
  float rstd = rsqrtf(ss * (1.f / E) - mu * mu + 1e-5f);
#pragma unroll
  for (int i = 0; i < 3; ++i) {
    int c = i * 256 + lane * 4;
    float4 wv = *(const float4*)(w + c);
    float4 bv = *(const float4*)(b + c);
    float y0 = (v[i].x - mu) * rstd * wv.x + bv.x;
    float y1 = (v[i].y - mu) * rstd * wv.y + bv.y;
    float y2 = (v[i].z - mu) * rstd * wv.z + bv.z;
    float y3 = (v[i].w - mu) * rstd * wv.w + bv.w;
    uint2 o;
    o.x = (unsigned)f2bf(y0) | ((unsigned)f2bf(y1) << 16);
    o.y = (unsigned)f2bf(y2) | ((unsigned)f2bf(y3) << 16);
    *(uint2*)(out + row * E + c) = o;
  }
}

// --------------------------- GEMM: C[M,N] = A[M,K] * W[N,K]^T + epilogue ----
template <int MODE, int TN>
__global__ __launch_bounds__(256) void gemm_bt(const unsigned short* __restrict__ A,
                                               const unsigned short* __restrict__ Bw,
                                               const float* __restrict__ bias,
                                               const float* __restrict__ resid,
                                               void* __restrict__ Cout, int K, int N) {
  __shared__ unsigned short Al[128 * 32];
  __shared__ unsigned short Bl[TN * 32];
  constexpr int NI = TN / 32;
  int tid = threadIdx.x;
  int lane = tid & 63, w = tid >> 6;
  int q4 = lane >> 4, m16 = lane & 15;
  int m0 = blockIdx.x * 128, n0 = blockIdx.y * TN;
  int wm = (w >> 1) * 64, wn = (w & 1) * (TN / 2);
  facc zf = {0.f, 0.f, 0.f, 0.f};
  facc acc[4][NI];
#pragma unroll
  for (int mi = 0; mi < 4; ++mi)
#pragma unroll
    for (int ni = 0; ni < NI; ++ni) acc[mi][ni] = zf;

  for (int k0 = 0; k0 < K; k0 += 32) {
    int c0 = tid, c1 = tid + 256;
    gl2lds16(A + (m0 + (c0 >> 2)) * K + k0 + (c0 & 3) * 8, &Al[c0 * 8]);
    gl2lds16(A + (m0 + (c1 >> 2)) * K + k0 + (c1 & 3) * 8, &Al[c1 * 8]);
    gl2lds16(Bw + (n0 + (c0 >> 2)) * K + k0 + (c0 & 3) * 8, &Bl[c0 * 8]);
    if constexpr (TN == 128)
      gl2lds16(Bw + (n0 + (c1 >> 2)) * K + k0 + (c1 & 3) * 8, &Bl[c1 * 8]);
    __syncthreads();
    bfrag a[4], bb[NI];
#pragma unroll
    for (int mi = 0; mi < 4; ++mi)
      a[mi] = *(const bfrag*)&Al[(wm + mi * 16 + m16) * 32 + q4 * 8];
#pragma unroll
    for (int ni = 0; ni < NI; ++ni)
      bb[ni] = *(const bfrag*)&Bl[(wn + ni * 16 + m16) * 32 + q4 * 8];
#pragma unroll
    for (int mi = 0; mi < 4; ++mi)
#pragma unroll
      for (int ni = 0; ni < NI; ++ni)
        acc[mi][ni] = mfma16(a[mi], bb[ni], acc[mi][ni]);
    __syncthreads();
  }

#pragma unroll
  for (int mi = 0; mi < 4; ++mi)
#pragma unroll
    for (int ni = 0; ni < NI; ++ni)
#pragma unroll
      for (int r = 0; r < 4; ++r) {
        int row = m0 + wm + mi * 16 + q4 * 4 + r;
        int col = n0 + wn + ni * 16 + m16;
        float vv = acc[mi][ni][r] + bias[col];
        if constexpr (MODE == 1) {
          ((float*)Cout)[row * N + col] = vv + resid[row * N + col];
        } else if constexpr (MODE == 2) {
          float g = vv / (1.f + __expf(-1.702f * vv));
          ((unsigned short*)Cout)[row * N + col] = f2bf(g);
        } else {
          ((unsigned short*)Cout)[row * N + col] = f2bf(vv);
        }
      }
}

// --------------------------- V transpose ------------------------------------
// qkv V-block [l,n][h*64+d] -> vt[by][d][l], by = h*4+n
__global__ __launch_bounds__(256) void vtrans_k(const unsigned short* __restrict__ qkv,
                                                unsigned short* __restrict__ vt) {
  __shared__ unsigned short T[64 * 72];
  int tid = threadIdx.x;
  int l0 = blockIdx.x * 64;
  int by = blockIdx.y;
  int n = by & 3, h = by >> 2;
#pragma unroll
  for (int i = 0; i < 2; ++i) {
    int u = i * 256 + tid;
    int r = u >> 3, c8 = u & 7;
    uint4 v4 = *(const uint4*)(qkv + ((l0 + r) * 4 + n) * 2304 + 1536 + h * 64 + c8 * 8);
    *(uint4*)&T[r * 72 + c8 * 8] = v4;
  }
  __syncthreads();
#pragma unroll
  for (int i = 0; i < 2; ++i) {
    int u = i * 256 + tid;
    int d = u >> 3, c8 = u & 7;
    unsigned short e[8];
#pragma unroll
    for (int jj = 0; jj < 8; ++jj) {
      int j = jj ^ (c8 & 7);
      e[j] = T[(c8 * 8 + j) * 72 + d];
    }
    uint4 o4;
    o4.x = (unsigned)e[0] | ((unsigned)e[1] << 16);
    o4.y = (unsigned)e[2] | ((unsigned)e[3] << 16);
    o4.z = (unsigned)e[4] | ((unsigned)e[5] << 16);
    o4.w = (unsigned)e[6] | ((unsigned)e[7] << 16);
    *(uint4*)(vt + ((size_t)by * 64 + d) * 2048 + l0 + c8 * 8) = o4;
  }
}

// --------------------------- Flash attention (v3) ----------------------------
// grid (16 q-tiles of 128, 48 by=(h*4+n)); 4 waves, 32 q-rows each.
// Kl: [kv][64] unpadded, 16B chunks XOR-swizzled by source addr (pos=c^(r&7)).
// Vtl: [d][128] unpadded, chunks XOR-swizzled (pos=c^(d&7)). Both gl2lds-staged
// asynchronously: K(t+1) issued mid-tile t, V(t+1) at tile t end; drains land
// behind >=1 compute phase. P: per-wave private 32x(PW=40) scratch, written and
// read by the same wave (no barrier), consumed in 4 kv-slices of 32.
#define PW 40
__global__ __launch_bounds__(256) void flash_k(const unsigned short* __restrict__ qkv,
                                               const unsigned short* __restrict__ vt,
                                               unsigned short* __restrict__ o) {
  __shared__ unsigned short Kl[128 * 64];    // 16 KB
  __shared__ unsigned short Vtl[64 * 128];   // 16 KB
  __shared__ unsigned short Pp[4 * 32 * PW]; // 10 KB
  int tid = threadIdx.x;
  int lane = tid & 63, w = tid >> 6;
  int q4 = lane >> 4, m16 = lane & 15;
  int qt = blockIdx.x;
  int by = blockIdx.y;
  int n = by & 3, h = by >> 2;
  const unsigned short* vtb = vt + (size_t)by * 64 * 2048;
  int wpb = w * 32 * PW;  // per-wave P base

  // Q fragments (A-layout), registers across the kv loop
  bfrag qf[2][2];
#pragma unroll
  for (int mi = 0; mi < 2; ++mi) {
    int l = qt * 128 + w * 32 + mi * 16 + m16;
#pragma unroll
    for (int ki = 0; ki < 2; ++ki)
      qf[mi][ki] = *(const bfrag*)(qkv + ((size_t)(l * 4 + n)) * 2304 + h * 64 + ki * 32 + q4 * 8);
  }

  facc zf = {0.f, 0.f, 0.f, 0.f};
  facc accO[2][4];
#pragma unroll
  for (int mi = 0; mi < 2; ++mi)
#pragma unroll
    for (int di = 0; di < 4; ++di) accO[mi][di] = zf;
  float lrow[2][4];
#pragma unroll
  for (int mi = 0; mi < 2; ++mi)
#pragma unroll
    for (int r = 0; r < 4; ++r) lrow[mi][r] = 0.f;

  const float cs = 0.125f * 1.44269504088896f;  // scale * log2(e)
  int ksw = m16 & 7;  // xor key for this lane's K/V fragment rows

  // tile 0 staging
#pragma unroll
  for (int i = 0; i < 4; ++i) {
    int F = i * 256 + tid;
    int r = F >> 3, ck = (F & 7) ^ (r & 7);
    gl2lds16(qkv + ((size_t)(r * 4 + n)) * 2304 + 768 + h * 64 + ck * 8, &Kl[F * 8]);
    int d = F >> 4, cv = (F & 15) ^ (d & 7);
    gl2lds16(vtb + d * 2048 + cv * 8, &Vtl[F * 8]);
  }
  __syncthreads();

  for (int kt = 0; kt < 16; ++kt) {
    // ---- S = Q K^T : 2(mi) x 8(ni) tiles, K=64 (2 steps) ----
    facc S[2][8];
#pragma unroll
    for (int mi = 0; mi < 2; ++mi)
#pragma unroll
      for (int ni = 0; ni < 8; ++ni) S[mi][ni] = zf;
#pragma unroll
    for (int ni = 0; ni < 8; ++ni)
#pragma unroll
      for (int ki = 0; ki < 2; ++ki) {
        bfrag bk = *(const bfrag*)&Kl[(ni * 16 + m16) * 64 + (((ki * 4 + q4) ^ ksw) << 3)];
#pragma unroll
        for (int mi = 0; mi < 2; ++mi)
          S[mi][ni] = mfma16(qf[mi][ki], bk, S[mi][ni]);
      }
    __syncthreads();   // B: K reads done (also drains V(t) staging)

    // restage K for tile kt+1 (async; drains at barrier C, one phase away)
    if (kt < 15) {
      int kv0 = (kt + 1) * 128;
#pragma unroll
      for (int i = 0; i < 4; ++i) {
        int F = i * 256 + tid;
        int r = F >> 3, ck = (F & 7) ^ (r & 7);
        gl2lds16(qkv + ((size_t)((kv0 + r) * 4 + n)) * 2304 + 768 + h * 64 + ck * 8, &Kl[F * 8]);
      }
    }

    // ---- sliced softmax + PV (P private to wave: no barriers) ----
#pragma unroll
    for (int si = 0; si < 4; ++si) {
#pragma unroll
      for (int mi = 0; mi < 2; ++mi)
#pragma unroll
        for (int r = 0; r < 4; ++r) {
          int prow = mi * 16 + q4 * 4 + r;
          float p0 = __builtin_amdgcn_exp2f(S[mi][2 * si][r] * cs);
          float p1 = __builtin_amdgcn_exp2f(S[mi][2 * si + 1][r] * cs);
          lrow[mi][r] += p0 + p1;
          Pp[wpb + prow * PW + m16]      = (unsigned short)(__float_as_uint(p0) >> 16);
          Pp[wpb + prow * PW + 16 + m16] = (unsigned short)(__float_as_uint(p1) >> 16);
        }
      bfrag pa[2];
#pragma unroll
      for (int mi = 0; mi < 2; ++mi)
        pa[mi] = *(const bfrag*)&Pp[wpb + (mi * 16 + m16) * PW + q4 * 8];
#pragma unroll
      for (int di = 0; di < 4; ++di) {
        bfrag bv = *(const bfrag*)&Vtl[(di * 16 + m16) * 128 + (((si * 4 + q4) ^ ksw) << 3)];
#pragma unroll
        for (int mi = 0; mi < 2; ++mi)
          accO[mi][di] = mfma16(pa[mi], bv, accO[mi][di]);
      }
    }
    __syncthreads();   // C: Vt reads done; K(t+1) staging drained here

    // restage V for tile kt+1 (async; drains at next barrier B)
    if (kt < 15) {
      int kv0 = (kt + 1) * 128;
#pragma unroll
      for (int i = 0; i < 4; ++i) {
        int F = i * 256 + tid;
        int d = F >> 4, cv = (F & 15) ^ (d & 7);
        gl2lds16(vtb + d * 2048 + kv0 + cv * 8, &Vtl[F * 8]);
      }
    }
  }

  // epilogue: reduce l across the 16 lanes sharing each row, write O
#pragma unroll
  for (int mi = 0; mi < 2; ++mi)
#pragma unroll
    for (int r = 0; r < 4; ++r) {
      float ls = lrow[mi][r];
      ls += __shfl_xor(ls, 1);
      ls += __shfl_xor(ls, 2);
      ls += __shfl_xor(ls, 4);
      ls += __shfl_xor(ls, 8);
      float inv = 1.f / ls;
      int l = qt * 128 + w * 32 + mi * 16 + q4 * 4 + r;
#pragma unroll
      for (int di = 0; di < 4; ++di) {
        int col = h * 64 + di * 16 + m16;
        o[(size_t)(l * 4 + n) * 768 + col] = f2bf(accO[mi][di][r] * inv);
      }
    }
}

// --------------------------- launcher ---------------------------------------
extern "C" void kernel_launch(void* const* d_in, const int* in_sizes, int n_in,
                              void* d_out, int out_size, void* d_ws, size_t ws_size,
                              hipStream_t stream) {
  (void)in_sizes; (void)n_in; (void)out_size; (void)ws_size;
  const float* x      = (const float*)d_in[0];
  const float* ln1_w  = (const float*)d_in[1];
  const float* ln1_b  = (const float*)d_in[2];
  const float* w_qkv  = (const float*)d_in[3];
  const float* b_qkv  = (const float*)d_in[4];
  const float* w_out  = (const float*)d_in[5];
  const float* b_out  = (const float*)d_in[6];
  const float* ln2_w  = (const float*)d_in[7];
  const float* ln2_b  = (const float*)d_in[8];
  const float* w_fc   = (const float*)d_in[9];
  const float* b_fc   = (const float*)d_in[10];
  const float* w_proj = (const float*)d_in[11];
  const float* b_proj = (const float*)d_in[12];

  char* ws = (char*)d_ws;
  unsigned short* qkv_bf  = (unsigned short*)(ws);
  unsigned short* o_bf    = (unsigned short*)(ws + 37748736);
  unsigned short* f_bf    = (unsigned short*)(ws);
  unsigned short* h_bf    = (unsigned short*)(ws + 50331648);
  float*          x1      = (float*)        (ws + 62914560);
  unsigned short* vt      = (unsigned short*)(ws + 62914560);  // dead before x1 written
  unsigned short* wqkv_bf = (unsigned short*)(ws + 88080384);
  unsigned short* wout_bf = (unsigned short*)(ws + 91619328);
  unsigned short* wfc_bf  = (unsigned short*)(ws + 92798976);
  unsigned short* wproj_bf= (unsigned short*)(ws + 97517568);

  cvt_bf16_k<<<1728, 256, 0, stream>>>(w_qkv,  wqkv_bf);
  cvt_bf16_k<<<576,  256, 0, stream>>>(w_out,  wout_bf);
  cvt_bf16_k<<<2304, 256, 0, stream>>>(w_fc,   wfc_bf);
  cvt_bf16_k<<<2304, 256, 0, stream>>>(w_proj, wproj_bf);

  ln_bf16_k<<<2048, 256, 0, stream>>>(x, ln1_w, ln1_b, h_bf);
  gemm_bt<0, 128><<<dim3(64, 18), 256, 0, stream>>>(h_bf, wqkv_bf, b_qkv, nullptr, qkv_bf, 768, 2304);
  vtrans_k<<<dim3(32, 48), 256, 0, stream>>>(qkv_bf, vt);
  flash_k<<<dim3(16, 48), 256, 0, stream>>>(qkv_bf, vt, o_bf);
  gemm_bt<1, 64><<<dim3(64, 12), 256, 0, stream>>>(o_bf, wout_bf, b_out, x, x1, 768, 768);
  ln_bf16_k<<<2048, 256, 0, stream>>>(x1, ln2_w, ln2_b, h_bf);
  gemm_bt<2, 128><<<dim3(64, 24), 256, 0, stream>>>(h_bf, wfc_bf, b_fc, nullptr, f_bf, 768, 3072);
  gemm_bt<1, 64><<<dim3(64, 12), 256, 0, stream>>>(f_bf, wproj_bf, b_proj, x1, (float*)d_out, 3072, 768);
}